// Round 5
// baseline (1713.573 us; speedup 1.0000x reference)
//
#include <hip/hip_runtime.h>
#include <hip/hip_bf16.h>
#include <math.h>

// B=2, S=2048, D=1024, H=16, HD=64. ALL fp32 (inputs AND output).
// Evidence: R1 bf16-decode of inputs -> NaN (inputs fp32); R2-R4 bf16-coded
// output -> absmax 1.88 garbage vs test's fp32 read; threshold 0.03125 ==
// 2% of refmax 1.5625 (relative, not a bf16 floor). Output must be fp32.
// Pipeline: QKV proj (3 GEMMs) -> flash attention -> out proj (1 GEMM).
// fp32 accumulate; Q/K/V/ctx staged fp32 in d_ws (64 MB).

#define Bdim  2
#define Sdim  2048
#define Ddim  1024
#define Hn    16
#define HDdim 64
#define Mdim  (Bdim * Sdim)   // 4096

// ---------------- GEMM: C[M,N] = A[M,K] @ W[K,N] + bias ----------------
// M=4096, N=K=1024. Tile 64x64, BK=16, 256 threads, 4x4 microtile. fp32.
// HEADS=true  -> fp32 out in [B,H,S,HD] (QKV); HEADS=false -> fp32 out [M,N].

template <bool HEADS>
__global__ __launch_bounds__(256)
void gemm64(const float* __restrict__ A, const float* __restrict__ W,
            const float* __restrict__ bias, float* __restrict__ outP)
{
    __shared__ float As[16][68];  // [k][m]
    __shared__ float Bs[16][68];  // [k][n]

    const int tid = threadIdx.x;
    const int tx = tid & 15, ty = tid >> 4;
    const int m0 = blockIdx.y * 64;
    const int n0 = blockIdx.x * 64;

    float acc[4][4] = {};

    const int lam = tid >> 2;          // 0..63  (m, A load)
    const int lak = (tid & 3) * 4;     // 0,4,8,12 (k, A load)
    const int lbk = tid >> 4;          // 0..15  (k, B load)
    const int lbn = (tid & 15) * 4;    // 0..60  (n, B load)

    for (int kk = 0; kk < Ddim; kk += 16) {
        {
            const float* ap = A + (size_t)(m0 + lam) * Ddim + kk + lak;
            float4 a4 = *(const float4*)ap;
            As[lak + 0][lam] = a4.x;
            As[lak + 1][lam] = a4.y;
            As[lak + 2][lam] = a4.z;
            As[lak + 3][lam] = a4.w;
        }
        {
            const float* bp = W + (size_t)(kk + lbk) * Ddim + n0 + lbn;
            *(float4*)&Bs[lbk][lbn] = *(const float4*)bp;
        }
        __syncthreads();

        #pragma unroll
        for (int k = 0; k < 16; ++k) {
            float4 a4 = *(const float4*)&As[k][ty * 4];
            float4 b4 = *(const float4*)&Bs[k][tx * 4];
            float av[4] = {a4.x, a4.y, a4.z, a4.w};
            float bv[4] = {b4.x, b4.y, b4.z, b4.w};
            #pragma unroll
            for (int i = 0; i < 4; ++i)
                #pragma unroll
                for (int j = 0; j < 4; ++j)
                    acc[i][j] = fmaf(av[i], bv[j], acc[i][j]);
        }
        __syncthreads();
    }

    float bvals[4];
    #pragma unroll
    for (int j = 0; j < 4; ++j) bvals[j] = bias[n0 + tx * 4 + j];

    #pragma unroll
    for (int i = 0; i < 4; ++i) {
        int m = m0 + ty * 4 + i;
        #pragma unroll
        for (int j = 0; j < 4; ++j) {
            int n = n0 + tx * 4 + j;
            float v = acc[i][j] + bvals[j];
            if constexpr (HEADS) {
                int b = m >> 11;        // m / S
                int s = m & 2047;       // m % S
                int h = n >> 6;         // n / HD
                int e = n & 63;         // n % HD
                outP[((((size_t)b * Hn + h) * Sdim + s) << 6) + e] = v;
            } else {
                outP[(size_t)m * Ddim + n] = v;
            }
        }
    }
}

// ---------------- Flash attention (causal, online softmax) ----------------
#define BQ 32
#define BK 32

__global__ __launch_bounds__(256)
void flash_attn(const float* __restrict__ Q, const float* __restrict__ K,
                const float* __restrict__ V, float* __restrict__ ctx)
{
    __shared__ float Qs[BQ][65];
    __shared__ float Ks[BK][65];
    __shared__ float Vs[BK][65];
    __shared__ float Ss[BQ][33];
    __shared__ float m_s[BQ], l_s[BQ], a_s[BQ];

    const int tid = threadIdx.x;
    const int bh = blockIdx.y;          // b*H + h
    const int qt = blockIdx.x;
    const int q0 = qt * BQ;
    const float scale = 0.125f;         // 1/sqrt(64)

    const float* Qp = Q + ((size_t)bh * Sdim + q0) * HDdim;
    const float* Kp = K + (size_t)bh * Sdim * HDdim;
    const float* Vp = V + (size_t)bh * Sdim * HDdim;

    for (int i = tid; i < BQ * HDdim; i += 256)
        Qs[i >> 6][i & 63] = Qp[i];
    if (tid < BQ) { m_s[tid] = -INFINITY; l_s[tid] = 0.f; }

    const int r  = tid & 31;
    const int g  = tid >> 5;
    const int c0 = g * 8;
    float o[8];
    #pragma unroll
    for (int i = 0; i < 8; ++i) o[i] = 0.f;

    for (int kt = 0; kt <= qt; ++kt) {
        const int k0 = kt * BK;
        __syncthreads();
        for (int i = tid; i < BK * HDdim; i += 256) {
            Ks[i >> 6][i & 63] = Kp[(size_t)k0 * HDdim + i];
            Vs[i >> 6][i & 63] = Vp[(size_t)k0 * HDdim + i];
        }
        __syncthreads();

        float dot[4] = {0.f, 0.f, 0.f, 0.f};
        #pragma unroll 8
        for (int e = 0; e < HDdim; ++e) {
            float qv = Qs[r][e];
            #pragma unroll
            for (int jj = 0; jj < 4; ++jj)
                dot[jj] = fmaf(qv, Ks[g * 4 + jj][e], dot[jj]);
        }
        #pragma unroll
        for (int jj = 0; jj < 4; ++jj) {
            int j = g * 4 + jj;
            bool valid = (k0 + j) <= (q0 + r);
            Ss[r][j] = valid ? dot[jj] * scale : -INFINITY;
        }
        __syncthreads();

        if (tid < BQ) {
            const int rr = tid;
            float mt = m_s[rr];
            #pragma unroll 8
            for (int j = 0; j < BK; ++j) mt = fmaxf(mt, Ss[rr][j]);
            float alpha = __expf(m_s[rr] - mt);
            float sum = 0.f;
            #pragma unroll 8
            for (int j = 0; j < BK; ++j) {
                float p = __expf(Ss[rr][j] - mt);
                Ss[rr][j] = p;
                sum += p;
            }
            l_s[rr] = l_s[rr] * alpha + sum;
            m_s[rr] = mt;
            a_s[rr] = alpha;
        }
        __syncthreads();

        float alpha = a_s[r];
        #pragma unroll
        for (int i = 0; i < 8; ++i) o[i] *= alpha;
        #pragma unroll 4
        for (int j = 0; j < BK; ++j) {
            float p = Ss[r][j];
            #pragma unroll
            for (int i = 0; i < 8; ++i)
                o[i] = fmaf(p, Vs[j][c0 + i], o[i]);
        }
    }

    __syncthreads();
    float inv_l = 1.0f / l_s[r];
    #pragma unroll
    for (int i = 0; i < 8; ++i) Ks[r][c0 + i] = o[i] * inv_l;
    __syncthreads();

    const int row = tid >> 3;
    const int col = (tid & 7) * 8;
    const int b = bh >> 4, h = bh & 15;
    size_t base = ((size_t)b * Sdim + q0 + row) * Ddim + h * HDdim + col;
    float4 v0 = make_float4(Ks[row][col + 0], Ks[row][col + 1],
                            Ks[row][col + 2], Ks[row][col + 3]);
    float4 v1 = make_float4(Ks[row][col + 4], Ks[row][col + 5],
                            Ks[row][col + 6], Ks[row][col + 7]);
    *(float4*)&ctx[base + 0] = v0;
    *(float4*)&ctx[base + 4] = v1;
}

// ---------------- launch ----------------
extern "C" void kernel_launch(void* const* d_in, const int* in_sizes, int n_in,
                              void* d_out, int out_size, void* d_ws, size_t ws_size,
                              hipStream_t stream)
{
    // Runtime input-order detection (R4: xi==0 -> dict order confirmed).
    const int NX = Mdim * Ddim;        // 4194304
    const int NW = Ddim * Ddim;        // 1048576

    int xi = 0, wi[4] = {1,3,5,7}, bi[4] = {2,4,6,8}, nw = 0, nb = 0;
    bool sized = true;
    for (int i = 0; i < 9; ++i) {
        if (in_sizes[i] == NX) xi = i;
        else if (in_sizes[i] == NW) { if (nw < 4) wi[nw++] = i; }
        else if (in_sizes[i] == Ddim) { if (nb < 4) bi[nb++] = i; }
        else sized = false;
    }

    int iWq, iWk, iWv, iWo, ibq, ibk, ibv, ibo;
    if (!sized || xi == 0) {
        // dict / insertion order: x, W_q, b_q, W_k, b_k, W_v, b_v, W_o, b_o
        xi = 0;
        iWq = 1; ibq = 2; iWk = 3; ibk = 4; iWv = 5; ibv = 6; iWo = 7; ibo = 8;
    } else {
        // sorted pytree order: W_k, W_o, W_q, W_v, b_k, b_o, b_q, b_v, x
        iWk = wi[0]; iWo = wi[1]; iWq = wi[2]; iWv = wi[3];
        ibk = bi[0]; ibo = bi[1]; ibq = bi[2]; ibv = bi[3];
    }

    const float* x  = (const float*)d_in[xi];
    const float* Wq = (const float*)d_in[iWq];
    const float* bq = (const float*)d_in[ibq];
    const float* Wk = (const float*)d_in[iWk];
    const float* bk = (const float*)d_in[ibk];
    const float* Wv = (const float*)d_in[iWv];
    const float* bv = (const float*)d_in[ibv];
    const float* Wo = (const float*)d_in[iWo];
    const float* bo = (const float*)d_in[ibo];
    float* out = (float*)d_out;        // fp32 output

    const size_t elems = (size_t)Mdim * Ddim;   // 4,194,304
    float* Qb = (float*)d_ws;
    float* Kb = Qb + elems;
    float* Vb = Kb + elems;
    float* Cb = Vb + elems;

    dim3 blk(256);
    dim3 gGemm(Ddim / 64, Mdim / 64);   // (16, 64)
    gemm64<true><<<gGemm, blk, 0, stream>>>(x, Wq, bq, Qb);
    gemm64<true><<<gGemm, blk, 0, stream>>>(x, Wk, bk, Kb);
    gemm64<true><<<gGemm, blk, 0, stream>>>(x, Wv, bv, Vb);

    dim3 gAttn(Sdim / BQ, Bdim * Hn);   // (64, 32)
    flash_attn<<<gAttn, blk, 0, stream>>>(Qb, Kb, Vb, Cb);

    gemm64<false><<<gGemm, blk, 0, stream>>>(Cb, Wo, bo, out);
}

// Round 6
// 637.034 us; speedup vs baseline: 2.6899x; 2.6899x over previous
//
#include <hip/hip_runtime.h>
#include <hip/hip_bf16.h>
#include <math.h>

// B=2, S=2048, D=1024, H=16, HD=64. Inputs fp32, output fp32 (R5: verified).
// R6: flash attention -> bf16 MFMA (16x16x32). QKV GEMMs write bf16
// (Q,K in [B,H,S,HD]; V transposed [B,H,HD,S] for key-contiguous PV frags).
// Final GEMM unchanged fp32.

#define Bdim  2
#define Sdim  2048
#define Ddim  1024
#define Hn    16
#define HDdim 64
#define Mdim  (Bdim * Sdim)   // 4096

typedef unsigned short ushort_t;
typedef __attribute__((ext_vector_type(8))) short bfrag;   // 8 bf16 (4 VGPR)
typedef __attribute__((ext_vector_type(4))) float f4;

__device__ __forceinline__ ushort_t f2bf(float f) {
    union { float f; unsigned int i; } c;
    c.f = f;
    unsigned int x = c.i;
    unsigned int r = (x + 0x7fffu + ((x >> 16) & 1u)) >> 16;  // RNE
    return (ushort_t)r;
}

// ---------------- GEMM: C[M,N] = A[M,K] @ W[K,N] + bias ----------------
// M=4096, N=K=1024. Tile 64x64, BK=16, 256 threads, 4x4 microtile. fp32 in.
// MODE 0: bf16 out [B,H,S,HD] (Q,K)   MODE 1: bf16 out [B,H,HD,S] (V^T)
// MODE 2: fp32 out [M,N] (final)

template <int MODE>
__global__ __launch_bounds__(256)
void gemm64(const float* __restrict__ A, const float* __restrict__ W,
            const float* __restrict__ bias, void* __restrict__ outP)
{
    __shared__ float As[16][68];  // [k][m]
    __shared__ float Bs[16][68];  // [k][n]

    const int tid = threadIdx.x;
    const int tx = tid & 15, ty = tid >> 4;
    const int m0 = blockIdx.y * 64;
    const int n0 = blockIdx.x * 64;

    float acc[4][4] = {};

    const int lam = tid >> 2;          // 0..63  (m, A load)
    const int lak = (tid & 3) * 4;     // 0,4,8,12 (k, A load)
    const int lbk = tid >> 4;          // 0..15  (k, B load)
    const int lbn = (tid & 15) * 4;    // 0..60  (n, B load)

    for (int kk = 0; kk < Ddim; kk += 16) {
        {
            const float* ap = A + (size_t)(m0 + lam) * Ddim + kk + lak;
            float4 a4 = *(const float4*)ap;
            As[lak + 0][lam] = a4.x;
            As[lak + 1][lam] = a4.y;
            As[lak + 2][lam] = a4.z;
            As[lak + 3][lam] = a4.w;
        }
        {
            const float* bp = W + (size_t)(kk + lbk) * Ddim + n0 + lbn;
            *(float4*)&Bs[lbk][lbn] = *(const float4*)bp;
        }
        __syncthreads();

        #pragma unroll
        for (int k = 0; k < 16; ++k) {
            float4 a4 = *(const float4*)&As[k][ty * 4];
            float4 b4 = *(const float4*)&Bs[k][tx * 4];
            float av[4] = {a4.x, a4.y, a4.z, a4.w};
            float bv[4] = {b4.x, b4.y, b4.z, b4.w};
            #pragma unroll
            for (int i = 0; i < 4; ++i)
                #pragma unroll
                for (int j = 0; j < 4; ++j)
                    acc[i][j] = fmaf(av[i], bv[j], acc[i][j]);
        }
        __syncthreads();
    }

    float bvals[4];
    #pragma unroll
    for (int j = 0; j < 4; ++j) bvals[j] = bias[n0 + tx * 4 + j];

    #pragma unroll
    for (int i = 0; i < 4; ++i) {
        int m = m0 + ty * 4 + i;
        #pragma unroll
        for (int j = 0; j < 4; ++j) {
            int n = n0 + tx * 4 + j;
            float v = acc[i][j] + bvals[j];
            int b = m >> 11;        // m / S
            int s = m & 2047;       // m % S
            int h = n >> 6;         // n / HD
            int e = n & 63;         // n % HD
            if constexpr (MODE == 0) {
                ((ushort_t*)outP)[((((size_t)b * Hn + h) * Sdim + s) << 6) + e] = f2bf(v);
            } else if constexpr (MODE == 1) {
                ((ushort_t*)outP)[(((size_t)b * Hn + h) * HDdim + e) * Sdim + s] = f2bf(v);
            } else {
                ((float*)outP)[(size_t)m * Ddim + n] = v;
            }
        }
    }
}

// ---------------- Flash attention: bf16 MFMA, causal, online softmax -------
// Block = 256 threads = 4 waves; wave w owns q rows [q0+16w, q0+16w+15].
// K-tiles of 32 keys. Per tile per wave:
//   S^T = K.Q^T : 4x mfma_f32_16x16x32_bf16  (C: row=key_loc=quad*4+r, col=q=lane&15)
//   softmax stats per q: in-lane over 8 + shfl_xor 16,32 (replicated)
//   P^T -> wave-private LDS PT[q][key] (bf16), no barrier (same-wave lgkmcnt)
//   O += P.V : 4x mfma (A=PT[m=q=lane&15][k=key=quad*8+j], B=Vs[k=key][n=d])
// Kt XOR-swizzled 16B blocks (2-way bank = free); Vs from V^T global, stride 40.

#define FA_BQ 64
#define FA_BK 32

__global__ __launch_bounds__(256)
void flash_mfma(const ushort_t* __restrict__ Q, const ushort_t* __restrict__ K,
                const ushort_t* __restrict__ Vt, float* __restrict__ ctx)
{
    __shared__ ushort_t Kt[32 * 64];        // swizzled
    __shared__ ushort_t Vs[64 * 40];        // [d][key], stride 40
    __shared__ ushort_t PT[4][16 * 40];     // per-wave [q][key], stride 40

    const int tid  = threadIdx.x;
    const int lane = tid & 63;
    const int w    = tid >> 6;
    const int bh   = blockIdx.y;
    const int qb   = (int)gridDim.x - 1 - (int)blockIdx.x;  // longest-first
    const int q0   = qb * FA_BQ;
    const int qw   = q0 + w * 16;
    const int l15  = lane & 15;
    const int quad = lane >> 4;
    const float scale = 0.125f;

    // Q B-fragments in registers: B[k=d][n=q], lane: q=l15, d=quad*8+j (+32*kb)
    const ushort_t* Qrow = Q + ((size_t)bh * Sdim + qw + l15) * HDdim;
    bfrag Qf0 = *(const bfrag*)(Qrow + quad * 8);
    bfrag Qf1 = *(const bfrag*)(Qrow + 32 + quad * 8);

    const ushort_t* Kp = K  + (size_t)bh * Sdim * HDdim;
    const ushort_t* Vp = Vt + (size_t)bh * HDdim * Sdim;
    ushort_t* PTw = PT[w];

    f4 O[4];
    #pragma unroll
    for (int c = 0; c < 4; ++c) O[c] = (f4){0.f, 0.f, 0.f, 0.f};
    float m_prev = -INFINITY, l_run = 0.f;

    const int ntiles = (q0 + FA_BQ) / FA_BK;
    for (int kt = 0; kt < ntiles; ++kt) {
        const int k0 = kt * FA_BK;
        __syncthreads();   // protect Kt/Vs from previous-tile readers
        {   // stage K tile: 32 rows x 64 bf16, XOR-swizzled 16B blocks
            int row = tid >> 3, blk = tid & 7;
            const ushort_t* src = Kp + (size_t)(k0 + row) * HDdim + blk * 8;
            *(bfrag*)&Kt[row * 64 + ((blk ^ row) & 7) * 8] = *(const bfrag*)src;
        }
        {   // stage V^T tile: 64 d-rows x 32 keys
            int d = tid >> 2, kk = (tid & 3) * 8;
            const ushort_t* src = Vp + (size_t)d * Sdim + k0 + kk;
            *(bfrag*)&Vs[d * 40 + kk] = *(const bfrag*)src;
        }
        __syncthreads();

        // S^T = K . Q^T  (two 16-key halves x two 32-d chunks)
        f4 ST[2];
        #pragma unroll
        for (int h = 0; h < 2; ++h) {
            int krow = h * 16 + l15;   // A m-index = key within tile
            bfrag a0 = *(const bfrag*)&Kt[krow * 64 + (((0 + quad) ^ krow) & 7) * 8];
            bfrag a1 = *(const bfrag*)&Kt[krow * 64 + (((4 + quad) ^ krow) & 7) * 8];
            f4 acc = (f4){0.f, 0.f, 0.f, 0.f};
            acc = __builtin_amdgcn_mfma_f32_16x16x32_bf16(a0, Qf0, acc, 0, 0, 0);
            acc = __builtin_amdgcn_mfma_f32_16x16x32_bf16(a1, Qf1, acc, 0, 0, 0);
            ST[h] = acc;
        }

        // scale + causal mask + row stats (q = l15, replicated over quads)
        const int q_g = qw + l15;
        float p[2][4];
        float mt = -INFINITY;
        #pragma unroll
        for (int h = 0; h < 2; ++h)
            #pragma unroll
            for (int r = 0; r < 4; ++r) {
                int key_g = k0 + h * 16 + quad * 4 + r;
                float v = (key_g <= q_g) ? ST[h][r] * scale : -INFINITY;
                p[h][r] = v;
                mt = fmaxf(mt, v);
            }
        mt = fmaxf(mt, __shfl_xor(mt, 16, 64));
        mt = fmaxf(mt, __shfl_xor(mt, 32, 64));
        float m_new = fmaxf(m_prev, mt);
        float alpha = __expf(m_prev - m_new);   // first tile: exp(-inf)=0
        float rsum = 0.f;
        #pragma unroll
        for (int h = 0; h < 2; ++h)
            #pragma unroll
            for (int r = 0; r < 4; ++r) {
                float e = __expf(p[h][r] - m_new);   // masked -> 0
                p[h][r] = e;
                rsum += e;
            }
        rsum += __shfl_xor(rsum, 16, 64);
        rsum += __shfl_xor(rsum, 32, 64);
        l_run = l_run * alpha + rsum;
        m_prev = m_new;

        // P^T -> PT[q][key] (bf16), wave-private: no block barrier needed
        #pragma unroll
        for (int h = 0; h < 2; ++h)
            #pragma unroll
            for (int r = 0; r < 4; ++r)
                PTw[l15 * 40 + h * 16 + quad * 4 + r] = f2bf(p[h][r]);

        // O rescale: alpha indexed by q; O rows are q=quad*4+r
        #pragma unroll
        for (int r = 0; r < 4; ++r) {
            float ar = __shfl(alpha, (lane & 48) + quad * 4 + r, 64);
            #pragma unroll
            for (int c = 0; c < 4; ++c) O[c][r] *= ar;
        }

        // PV: A = PT (m=q=l15, k=key=quad*8+j); B = Vs (k=key, n=d chunk)
        bfrag pA = *(const bfrag*)&PTw[l15 * 40 + quad * 8];
        #pragma unroll
        for (int c = 0; c < 4; ++c) {
            bfrag vB = *(const bfrag*)&Vs[(c * 16 + l15) * 40 + quad * 8];
            O[c] = __builtin_amdgcn_mfma_f32_16x16x32_bf16(pA, vB, O[c], 0, 0, 0);
        }
    }

    // epilogue: O[c][r] -> ctx[b, s=qw+quad*4+r, h*64 + c*16 + l15] (fp32)
    const int b = bh >> 4, h = bh & 15;
    #pragma unroll
    for (int r = 0; r < 4; ++r) {
        float inv_l = 1.0f / __shfl(l_run, (lane & 48) + quad * 4 + r, 64);
        size_t base = ((size_t)b * Sdim + qw + quad * 4 + r) * Ddim + h * HDdim + l15;
        #pragma unroll
        for (int c = 0; c < 4; ++c)
            ctx[base + c * 16] = O[c][r] * inv_l;
    }
}

// ---------------- launch ----------------
extern "C" void kernel_launch(void* const* d_in, const int* in_sizes, int n_in,
                              void* d_out, int out_size, void* d_ws, size_t ws_size,
                              hipStream_t stream)
{
    // Input-order detection (R4/R5: dict order confirmed; keep fallback).
    const int NX = Mdim * Ddim;
    const int NW = Ddim * Ddim;
    int xi = 0, wi[4] = {1, 3, 5, 7}, bi[4] = {2, 4, 6, 8}, nw = 0, nb = 0;
    bool sized = true;
    for (int i = 0; i < 9; ++i) {
        if (in_sizes[i] == NX) xi = i;
        else if (in_sizes[i] == NW) { if (nw < 4) wi[nw++] = i; }
        else if (in_sizes[i] == Ddim) { if (nb < 4) bi[nb++] = i; }
        else sized = false;
    }
    int iWq, iWk, iWv, iWo, ibq, ibk, ibv, ibo;
    if (!sized || xi == 0) {
        xi = 0; iWq = 1; ibq = 2; iWk = 3; ibk = 4; iWv = 5; ibv = 6; iWo = 7; ibo = 8;
    } else {
        iWk = wi[0]; iWo = wi[1]; iWq = wi[2]; iWv = wi[3];
        ibk = bi[0]; ibo = bi[1]; ibq = bi[2]; ibv = bi[3];
    }

    const float* x  = (const float*)d_in[xi];
    const float* Wq = (const float*)d_in[iWq];
    const float* bq = (const float*)d_in[ibq];
    const float* Wk = (const float*)d_in[iWk];
    const float* bk = (const float*)d_in[ibk];
    const float* Wv = (const float*)d_in[iWv];
    const float* bv = (const float*)d_in[ibv];
    const float* Wo = (const float*)d_in[iWo];
    const float* bo = (const float*)d_in[ibo];
    float* out = (float*)d_out;

    const size_t elems = (size_t)Mdim * Ddim;   // 4,194,304
    ushort_t* Qb  = (ushort_t*)d_ws;            // 8 MB
    ushort_t* Kb  = Qb + elems;                 // 8 MB
    ushort_t* Vtb = Kb + elems;                 // 8 MB
    float*    Cb  = (float*)(Vtb + elems);      // 16 MB

    dim3 blk(256);
    dim3 gGemm(Ddim / 64, Mdim / 64);   // (16, 64)
    gemm64<0><<<gGemm, blk, 0, stream>>>(x, Wq, bq, Qb);
    gemm64<0><<<gGemm, blk, 0, stream>>>(x, Wk, bk, Kb);
    gemm64<1><<<gGemm, blk, 0, stream>>>(x, Wv, bv, Vtb);

    dim3 gAttn(Sdim / FA_BQ, Bdim * Hn);   // (32, 32)
    flash_mfma<<<gAttn, blk, 0, stream>>>(Qb, Kb, Vtb, Cb);

    gemm64<2><<<gGemm, blk, 0, stream>>>(Cb, Wo, bo, out);
}

// Round 7
// 254.557 us; speedup vs baseline: 6.7316x; 2.5025x over previous
//
#include <hip/hip_runtime.h>
#include <hip/hip_bf16.h>
#include <math.h>

// B=2, S=2048, D=1024, H=16, HD=64. Inputs fp32, output fp32.
// R7: all GEMMs -> bf16 MFMA (m97 structure: 128x128 tile, BK=32,
// global_load_lds width=16, NT layout). QKV fused into one N=3072 GEMM.
// Flash attention (R6 MFMA version) now writes bf16 ctx.

#define Bdim  2
#define Sdim  2048
#define Ddim  1024
#define Hn    16
#define HDdim 64
#define Mdim  (Bdim * Sdim)   // 4096

typedef unsigned short ushort_t;
typedef __attribute__((ext_vector_type(8))) short bfrag;   // 8 bf16 (4 VGPR)
typedef __attribute__((ext_vector_type(4))) float f4;

__device__ __forceinline__ ushort_t f2bf(float f) {
    union { float f; unsigned int i; } c;
    c.f = f;
    unsigned int x = c.i;
    unsigned int r = (x + 0x7fffu + ((x >> 16) & 1u)) >> 16;  // RNE
    return (ushort_t)r;
}

__device__ __forceinline__ void glds16(const void* g, void* l) {
    __builtin_amdgcn_global_load_lds(
        (const __attribute__((address_space(1))) unsigned int*)g,
        (__attribute__((address_space(3))) unsigned int*)l, 16, 0, 0);
}

// ---------------- cast x: fp32 [M][K] -> bf16 same layout ----------------
__global__ __launch_bounds__(256)
void cast_x(const float* __restrict__ x, ushort_t* __restrict__ xb)
{
    size_t i = ((size_t)blockIdx.x * 256 + threadIdx.x) * 8;
    float4 a = *(const float4*)(x + i);
    float4 b = *(const float4*)(x + i + 4);
    ushort_t o[8] = {f2bf(a.x), f2bf(a.y), f2bf(a.z), f2bf(a.w),
                     f2bf(b.x), f2bf(b.y), f2bf(b.z), f2bf(b.w)};
    *(bfrag*)(xb + i) = *(const bfrag*)o;
}

// ------------- transpose-cast weights: W[k][n] fp32 -> Wt[n][k] bf16 -------
// grid (16,16,4): 64x64 tiles; z selects matrix (0..2 -> qkvT, 3 -> oT).
__global__ __launch_bounds__(256)
void wtrans(const float* __restrict__ W0, const float* __restrict__ W1,
            const float* __restrict__ W2, const float* __restrict__ W3,
            ushort_t* __restrict__ qkvT, ushort_t* __restrict__ oT)
{
    __shared__ ushort_t t[64][72];   // [n][k], padded
    const int tid = threadIdx.x;
    const int z = blockIdx.z;
    const float* W = (z == 0) ? W0 : (z == 1) ? W1 : (z == 2) ? W2 : W3;
    const int k0 = blockIdx.y * 64, n0 = blockIdx.x * 64;

    const int r = tid >> 4, c4 = (tid & 15) * 4;
    #pragma unroll
    for (int rr = 0; rr < 4; ++rr) {
        int k = r + rr * 16;
        float4 v = *(const float4*)&W[(size_t)(k0 + k) * Ddim + n0 + c4];
        t[c4 + 0][k] = f2bf(v.x);
        t[c4 + 1][k] = f2bf(v.y);
        t[c4 + 2][k] = f2bf(v.z);
        t[c4 + 3][k] = f2bf(v.w);
    }
    __syncthreads();
    ushort_t* out = (z < 3) ? (qkvT + (size_t)z * Ddim * Ddim) : oT;
    const int n = tid >> 2, kc = (tid & 3) * 16;
    *(bfrag*)&out[(size_t)(n0 + n) * Ddim + k0 + kc] = *(const bfrag*)&t[n][kc];
    *(bfrag*)&out[(size_t)(n0 + n) * Ddim + k0 + kc + 8] = *(const bfrag*)&t[n][kc + 8];
}

// ---------------- MFMA GEMM (m97 structure, NT) ----------------
// C[M,Ntot] = A[M,K]bf16 @ Bt[Ntot,K]bf16^T + bias. K=1024, BK=32,
// 128x128 tile, 256 thr = 4 waves (2x2), wave = 4x4 of 16x16x32 MFMA.
// MODE 0: Ntot=3072 fused QKV; epilogue scatters bf16 to Q,K [B,H,S,HD], Vt [B,H,HD,S].
// MODE 1: Ntot=1024; fp32 out [M,N].
template <int MODE>
__global__ __launch_bounds__(256)
void gemm_mfma(const ushort_t* __restrict__ A, const ushort_t* __restrict__ Bt,
               const float* __restrict__ bQ, const float* __restrict__ bK,
               const float* __restrict__ bV,
               ushort_t* __restrict__ oQ, ushort_t* __restrict__ oK,
               ushort_t* __restrict__ oVt, float* __restrict__ oF)
{
    __shared__ ushort_t As[128 * 32];   // [row][k], 64 B rows
    __shared__ ushort_t Bs[128 * 32];

    const int tid  = threadIdx.x;
    const int lane = tid & 63;
    const int w    = tid >> 6;
    const int l15  = lane & 15;
    const int quad = lane >> 4;
    const int wr   = w >> 1, wc = w & 1;
    const int m0 = blockIdx.y * 128;
    const int n0 = blockIdx.x * 128;

    f4 acc[4][4];
    #pragma unroll
    for (int i = 0; i < 4; ++i)
        #pragma unroll
        for (int j = 0; j < 4; ++j) acc[i][j] = (f4){0.f, 0.f, 0.f, 0.f};

    // staging: wave w stages rows [w*32, w*32+32) of both tiles as 2x 16-row chunks
    const int srow  = w * 32 + (lane >> 2);
    const int selem = (lane & 3) * 8;          // halves within 64B row
    const ushort_t* gA = A  + (size_t)(m0 + srow) * Ddim + selem;
    const ushort_t* gB = Bt + (size_t)(n0 + srow) * Ddim + selem;
    char* lA0 = (char*)As + (w * 32) * 64;
    char* lB0 = (char*)Bs + (w * 32) * 64;

    for (int kk = 0; kk < Ddim; kk += 32) {
        __syncthreads();
        glds16(gA + kk,              lA0);
        glds16(gA + 16 * Ddim + kk,  lA0 + 1024);
        glds16(gB + kk,              lB0);
        glds16(gB + 16 * Ddim + kk,  lB0 + 1024);
        __syncthreads();

        bfrag Af[4], Bf[4];
        #pragma unroll
        for (int i = 0; i < 4; ++i)
            Af[i] = *(const bfrag*)&As[(wr * 64 + i * 16 + l15) * 32 + quad * 8];
        #pragma unroll
        for (int j = 0; j < 4; ++j)
            Bf[j] = *(const bfrag*)&Bs[(wc * 64 + j * 16 + l15) * 32 + quad * 8];
        #pragma unroll
        for (int i = 0; i < 4; ++i)
            #pragma unroll
            for (int j = 0; j < 4; ++j)
                acc[i][j] = __builtin_amdgcn_mfma_f32_16x16x32_bf16(Af[i], Bf[j], acc[i][j], 0, 0, 0);
    }

    // epilogue
    if constexpr (MODE == 0) {
        const int sel   = n0 >> 10;            // 0=Q,1=K,2=V (block never straddles)
        const int dbase = n0 & 1023;
        const float* bias = (sel == 0) ? bQ : (sel == 1) ? bK : bV;
        ushort_t* dst = (sel == 0) ? oQ : (sel == 1) ? oK : oVt;
        #pragma unroll
        for (int j = 0; j < 4; ++j) {
            int dn = dbase + wc * 64 + j * 16 + l15;
            float bv = bias[dn];
            int h = dn >> 6, e = dn & 63;
            #pragma unroll
            for (int i = 0; i < 4; ++i) {
                #pragma unroll
                for (int r = 0; r < 4; ++r) {
                    int m = m0 + wr * 64 + i * 16 + quad * 4 + r;
                    int b = m >> 11, s = m & 2047;
                    float v = acc[i][j][r] + bv;
                    if (sel < 2)
                        dst[((((size_t)b * Hn + h) * Sdim + s) << 6) + e] = f2bf(v);
                    else
                        dst[(((size_t)b * Hn + h) * HDdim + e) * Sdim + s] = f2bf(v);
                }
            }
        }
    } else {
        #pragma unroll
        for (int j = 0; j < 4; ++j) {
            int n = n0 + wc * 64 + j * 16 + l15;
            float bv = bQ[n];   // bo
            #pragma unroll
            for (int i = 0; i < 4; ++i)
                #pragma unroll
                for (int r = 0; r < 4; ++r) {
                    int m = m0 + wr * 64 + i * 16 + quad * 4 + r;
                    oF[(size_t)m * Ddim + n] = acc[i][j][r] + bv;
                }
        }
    }
}

// ---------------- Flash attention: bf16 MFMA, causal, online softmax -------
#define FA_BQ 64
#define FA_BK 32

__global__ __launch_bounds__(256)
void flash_mfma(const ushort_t* __restrict__ Q, const ushort_t* __restrict__ K,
                const ushort_t* __restrict__ Vt, ushort_t* __restrict__ ctx)
{
    __shared__ ushort_t Kt[32 * 64];        // swizzled
    __shared__ ushort_t Vs[64 * 40];        // [d][key], stride 40
    __shared__ ushort_t PT[4][16 * 40];     // per-wave [q][key], stride 40

    const int tid  = threadIdx.x;
    const int lane = tid & 63;
    const int w    = tid >> 6;
    const int bh   = blockIdx.y;
    const int qb   = (int)gridDim.x - 1 - (int)blockIdx.x;  // longest-first
    const int q0   = qb * FA_BQ;
    const int qw   = q0 + w * 16;
    const int l15  = lane & 15;
    const int quad = lane >> 4;
    const float scale = 0.125f;

    const ushort_t* Qrow = Q + ((size_t)bh * Sdim + qw + l15) * HDdim;
    bfrag Qf0 = *(const bfrag*)(Qrow + quad * 8);
    bfrag Qf1 = *(const bfrag*)(Qrow + 32 + quad * 8);

    const ushort_t* Kp = K  + (size_t)bh * Sdim * HDdim;
    const ushort_t* Vp = Vt + (size_t)bh * HDdim * Sdim;
    ushort_t* PTw = PT[w];

    f4 O[4];
    #pragma unroll
    for (int c = 0; c < 4; ++c) O[c] = (f4){0.f, 0.f, 0.f, 0.f};
    float m_prev = -INFINITY, l_run = 0.f;

    const int ntiles = (q0 + FA_BQ) / FA_BK;
    for (int kt = 0; kt < ntiles; ++kt) {
        const int k0 = kt * FA_BK;
        __syncthreads();
        {   // stage K tile: 32 rows x 64 bf16, XOR-swizzled 16B blocks
            int row = tid >> 3, blk = tid & 7;
            const ushort_t* src = Kp + (size_t)(k0 + row) * HDdim + blk * 8;
            *(bfrag*)&Kt[row * 64 + ((blk ^ row) & 7) * 8] = *(const bfrag*)src;
        }
        {   // stage V^T tile: 64 d-rows x 32 keys
            int d = tid >> 2, kk2 = (tid & 3) * 8;
            const ushort_t* src = Vp + (size_t)d * Sdim + k0 + kk2;
            *(bfrag*)&Vs[d * 40 + kk2] = *(const bfrag*)src;
        }
        __syncthreads();

        f4 ST[2];
        #pragma unroll
        for (int h = 0; h < 2; ++h) {
            int krow = h * 16 + l15;
            bfrag a0 = *(const bfrag*)&Kt[krow * 64 + (((0 + quad) ^ krow) & 7) * 8];
            bfrag a1 = *(const bfrag*)&Kt[krow * 64 + (((4 + quad) ^ krow) & 7) * 8];
            f4 s = (f4){0.f, 0.f, 0.f, 0.f};
            s = __builtin_amdgcn_mfma_f32_16x16x32_bf16(a0, Qf0, s, 0, 0, 0);
            s = __builtin_amdgcn_mfma_f32_16x16x32_bf16(a1, Qf1, s, 0, 0, 0);
            ST[h] = s;
        }

        const int q_g = qw + l15;
        float p[2][4];
        float mt = -INFINITY;
        #pragma unroll
        for (int h = 0; h < 2; ++h)
            #pragma unroll
            for (int r = 0; r < 4; ++r) {
                int key_g = k0 + h * 16 + quad * 4 + r;
                float v = (key_g <= q_g) ? ST[h][r] * scale : -INFINITY;
                p[h][r] = v;
                mt = fmaxf(mt, v);
            }
        mt = fmaxf(mt, __shfl_xor(mt, 16, 64));
        mt = fmaxf(mt, __shfl_xor(mt, 32, 64));
        float m_new = fmaxf(m_prev, mt);
        float alpha = __expf(m_prev - m_new);
        float rsum = 0.f;
        #pragma unroll
        for (int h = 0; h < 2; ++h)
            #pragma unroll
            for (int r = 0; r < 4; ++r) {
                float e = __expf(p[h][r] - m_new);
                p[h][r] = e;
                rsum += e;
            }
        rsum += __shfl_xor(rsum, 16, 64);
        rsum += __shfl_xor(rsum, 32, 64);
        l_run = l_run * alpha + rsum;
        m_prev = m_new;

        #pragma unroll
        for (int h = 0; h < 2; ++h)
            #pragma unroll
            for (int r = 0; r < 4; ++r)
                PTw[l15 * 40 + h * 16 + quad * 4 + r] = f2bf(p[h][r]);

        #pragma unroll
        for (int r = 0; r < 4; ++r) {
            float ar = __shfl(alpha, (lane & 48) + quad * 4 + r, 64);
            #pragma unroll
            for (int c = 0; c < 4; ++c) O[c][r] *= ar;
        }

        bfrag pA = *(const bfrag*)&PTw[l15 * 40 + quad * 8];
        #pragma unroll
        for (int c = 0; c < 4; ++c) {
            bfrag vB = *(const bfrag*)&Vs[(c * 16 + l15) * 40 + quad * 8];
            O[c] = __builtin_amdgcn_mfma_f32_16x16x32_bf16(pA, vB, O[c], 0, 0, 0);
        }
    }

    // epilogue: bf16 ctx [B,S,D]
    const int b = bh >> 4, h = bh & 15;
    #pragma unroll
    for (int r = 0; r < 4; ++r) {
        float inv_l = 1.0f / __shfl(l_run, (lane & 48) + quad * 4 + r, 64);
        size_t base = ((size_t)b * Sdim + qw + quad * 4 + r) * Ddim + h * HDdim + l15;
        #pragma unroll
        for (int c = 0; c < 4; ++c)
            ctx[base + c * 16] = f2bf(O[c][r] * inv_l);
    }
}

// ---------------- launch ----------------
extern "C" void kernel_launch(void* const* d_in, const int* in_sizes, int n_in,
                              void* d_out, int out_size, void* d_ws, size_t ws_size,
                              hipStream_t stream)
{
    const int NX = Mdim * Ddim;
    const int NW = Ddim * Ddim;
    int xi = 0, wi[4] = {1, 3, 5, 7}, bi[4] = {2, 4, 6, 8}, nw = 0, nb = 0;
    bool sized = true;
    for (int i = 0; i < 9; ++i) {
        if (in_sizes[i] == NX) xi = i;
        else if (in_sizes[i] == NW) { if (nw < 4) wi[nw++] = i; }
        else if (in_sizes[i] == Ddim) { if (nb < 4) bi[nb++] = i; }
        else sized = false;
    }
    int iWq, iWk, iWv, iWo, ibq, ibk, ibv, ibo;
    if (!sized || xi == 0) {
        xi = 0; iWq = 1; ibq = 2; iWk = 3; ibk = 4; iWv = 5; ibv = 6; iWo = 7; ibo = 8;
    } else {
        iWk = wi[0]; iWo = wi[1]; iWq = wi[2]; iWv = wi[3];
        ibk = bi[0]; ibo = bi[1]; ibq = bi[2]; ibv = bi[3];
    }

    const float* x  = (const float*)d_in[xi];
    const float* Wq = (const float*)d_in[iWq];
    const float* bq = (const float*)d_in[ibq];
    const float* Wk = (const float*)d_in[iWk];
    const float* bk = (const float*)d_in[ibk];
    const float* Wv = (const float*)d_in[iWv];
    const float* bv = (const float*)d_in[ibv];
    const float* Wo = (const float*)d_in[iWo];
    const float* bo = (const float*)d_in[ibo];
    float* out = (float*)d_out;

    const size_t elems = (size_t)Mdim * Ddim;   // 4,194,304
    const size_t welems = (size_t)Ddim * Ddim;  // 1,048,576
    ushort_t* Qb    = (ushort_t*)d_ws;          // 8 MB
    ushort_t* Kb    = Qb + elems;               // 8 MB
    ushort_t* Vtb   = Kb + elems;               // 8 MB
    ushort_t* Cb    = Vtb + elems;              // 8 MB
    ushort_t* xb    = Cb + elems;               // 8 MB
    ushort_t* qkvT  = xb + elems;               // 6 MB
    ushort_t* WoT   = qkvT + 3 * welems;        // 2 MB

    dim3 blk(256);
    cast_x<<<dim3(Mdim * Ddim / (256 * 8)), blk, 0, stream>>>(x, xb);
    wtrans<<<dim3(16, 16, 4), blk, 0, stream>>>(Wq, Wk, Wv, Wo, qkvT, WoT);

    // fused QKV: N = 3072
    gemm_mfma<0><<<dim3(3 * Ddim / 128, Mdim / 128), blk, 0, stream>>>(
        xb, qkvT, bq, bk, bv, Qb, Kb, Vtb, nullptr);

    dim3 gAttn(Sdim / FA_BQ, Bdim * Hn);   // (32, 32)
    flash_mfma<<<gAttn, blk, 0, stream>>>(Qb, Kb, Vtb, Cb);

    gemm_mfma<1><<<dim3(Ddim / 128, Mdim / 128), blk, 0, stream>>>(
        Cb, WoT, bo, nullptr, nullptr, nullptr, nullptr, nullptr, out);
}

// Round 8
// 248.208 us; speedup vs baseline: 6.9038x; 1.0256x over previous
//
#include <hip/hip_runtime.h>
#include <hip/hip_bf16.h>
#include <math.h>

// B=2, S=2048, D=1024, H=16, HD=64. Inputs fp32, output fp32.
// R8: flash_mfma gets register-prefetch double-buffered K/V staging
// (global-load latency overlapped with compute), wave-level skip of
// fully-masked diagonal tiles, packed b64 P-transpose writes.
// GEMMs (m97-style bf16 MFMA, fused QKV) unchanged from R7.

#define Bdim  2
#define Sdim  2048
#define Ddim  1024
#define Hn    16
#define HDdim 64
#define Mdim  (Bdim * Sdim)   // 4096

typedef unsigned short ushort_t;
typedef __attribute__((ext_vector_type(8))) short bfrag;   // 8 bf16 (4 VGPR)
typedef __attribute__((ext_vector_type(4))) float f4;

__device__ __forceinline__ ushort_t f2bf(float f) {
    union { float f; unsigned int i; } c;
    c.f = f;
    unsigned int x = c.i;
    unsigned int r = (x + 0x7fffu + ((x >> 16) & 1u)) >> 16;  // RNE
    return (ushort_t)r;
}

__device__ __forceinline__ void glds16(const void* g, void* l) {
    __builtin_amdgcn_global_load_lds(
        (const __attribute__((address_space(1))) unsigned int*)g,
        (__attribute__((address_space(3))) unsigned int*)l, 16, 0, 0);
}

// ---------------- cast x: fp32 [M][K] -> bf16 same layout ----------------
__global__ __launch_bounds__(256)
void cast_x(const float* __restrict__ x, ushort_t* __restrict__ xb)
{
    size_t i = ((size_t)blockIdx.x * 256 + threadIdx.x) * 8;
    float4 a = *(const float4*)(x + i);
    float4 b = *(const float4*)(x + i + 4);
    ushort_t o[8] = {f2bf(a.x), f2bf(a.y), f2bf(a.z), f2bf(a.w),
                     f2bf(b.x), f2bf(b.y), f2bf(b.z), f2bf(b.w)};
    *(bfrag*)(xb + i) = *(const bfrag*)o;
}

// ------------- transpose-cast weights: W[k][n] fp32 -> Wt[n][k] bf16 -------
__global__ __launch_bounds__(256)
void wtrans(const float* __restrict__ W0, const float* __restrict__ W1,
            const float* __restrict__ W2, const float* __restrict__ W3,
            ushort_t* __restrict__ qkvT, ushort_t* __restrict__ oT)
{
    __shared__ ushort_t t[64][72];   // [n][k], padded
    const int tid = threadIdx.x;
    const int z = blockIdx.z;
    const float* W = (z == 0) ? W0 : (z == 1) ? W1 : (z == 2) ? W2 : W3;
    const int k0 = blockIdx.y * 64, n0 = blockIdx.x * 64;

    const int r = tid >> 4, c4 = (tid & 15) * 4;
    #pragma unroll
    for (int rr = 0; rr < 4; ++rr) {
        int k = r + rr * 16;
        float4 v = *(const float4*)&W[(size_t)(k0 + k) * Ddim + n0 + c4];
        t[c4 + 0][k] = f2bf(v.x);
        t[c4 + 1][k] = f2bf(v.y);
        t[c4 + 2][k] = f2bf(v.z);
        t[c4 + 3][k] = f2bf(v.w);
    }
    __syncthreads();
    ushort_t* out = (z < 3) ? (qkvT + (size_t)z * Ddim * Ddim) : oT;
    const int n = tid >> 2, kc = (tid & 3) * 16;
    *(bfrag*)&out[(size_t)(n0 + n) * Ddim + k0 + kc] = *(const bfrag*)&t[n][kc];
    *(bfrag*)&out[(size_t)(n0 + n) * Ddim + k0 + kc + 8] = *(const bfrag*)&t[n][kc + 8];
}

// ---------------- MFMA GEMM (m97 structure, NT) ----------------
// MODE 0: Ntot=3072 fused QKV; scatter bf16 to Q,K [B,H,S,HD], Vt [B,H,HD,S].
// MODE 1: Ntot=1024; fp32 out [M,N].
template <int MODE>
__global__ __launch_bounds__(256)
void gemm_mfma(const ushort_t* __restrict__ A, const ushort_t* __restrict__ Bt,
               const float* __restrict__ bQ, const float* __restrict__ bK,
               const float* __restrict__ bV,
               ushort_t* __restrict__ oQ, ushort_t* __restrict__ oK,
               ushort_t* __restrict__ oVt, float* __restrict__ oF)
{
    __shared__ ushort_t As[128 * 32];   // [row][k], 64 B rows
    __shared__ ushort_t Bs[128 * 32];

    const int tid  = threadIdx.x;
    const int lane = tid & 63;
    const int w    = tid >> 6;
    const int l15  = lane & 15;
    const int quad = lane >> 4;
    const int wr   = w >> 1, wc = w & 1;
    const int m0 = blockIdx.y * 128;
    const int n0 = blockIdx.x * 128;

    f4 acc[4][4];
    #pragma unroll
    for (int i = 0; i < 4; ++i)
        #pragma unroll
        for (int j = 0; j < 4; ++j) acc[i][j] = (f4){0.f, 0.f, 0.f, 0.f};

    const int srow  = w * 32 + (lane >> 2);
    const int selem = (lane & 3) * 8;
    const ushort_t* gA = A  + (size_t)(m0 + srow) * Ddim + selem;
    const ushort_t* gB = Bt + (size_t)(n0 + srow) * Ddim + selem;
    char* lA0 = (char*)As + (w * 32) * 64;
    char* lB0 = (char*)Bs + (w * 32) * 64;

    for (int kk = 0; kk < Ddim; kk += 32) {
        __syncthreads();
        glds16(gA + kk,              lA0);
        glds16(gA + 16 * Ddim + kk,  lA0 + 1024);
        glds16(gB + kk,              lB0);
        glds16(gB + 16 * Ddim + kk,  lB0 + 1024);
        __syncthreads();

        bfrag Af[4], Bf[4];
        #pragma unroll
        for (int i = 0; i < 4; ++i)
            Af[i] = *(const bfrag*)&As[(wr * 64 + i * 16 + l15) * 32 + quad * 8];
        #pragma unroll
        for (int j = 0; j < 4; ++j)
            Bf[j] = *(const bfrag*)&Bs[(wc * 64 + j * 16 + l15) * 32 + quad * 8];
        #pragma unroll
        for (int i = 0; i < 4; ++i)
            #pragma unroll
            for (int j = 0; j < 4; ++j)
                acc[i][j] = __builtin_amdgcn_mfma_f32_16x16x32_bf16(Af[i], Bf[j], acc[i][j], 0, 0, 0);
    }

    if constexpr (MODE == 0) {
        const int sel   = n0 >> 10;
        const int dbase = n0 & 1023;
        const float* bias = (sel == 0) ? bQ : (sel == 1) ? bK : bV;
        ushort_t* dst = (sel == 0) ? oQ : (sel == 1) ? oK : oVt;
        #pragma unroll
        for (int j = 0; j < 4; ++j) {
            int dn = dbase + wc * 64 + j * 16 + l15;
            float bv = bias[dn];
            int h = dn >> 6, e = dn & 63;
            #pragma unroll
            for (int i = 0; i < 4; ++i) {
                #pragma unroll
                for (int r = 0; r < 4; ++r) {
                    int m = m0 + wr * 64 + i * 16 + quad * 4 + r;
                    int b = m >> 11, s = m & 2047;
                    float v = acc[i][j][r] + bv;
                    if (sel < 2)
                        dst[((((size_t)b * Hn + h) * Sdim + s) << 6) + e] = f2bf(v);
                    else
                        dst[(((size_t)b * Hn + h) * HDdim + e) * Sdim + s] = f2bf(v);
                }
            }
        }
    } else {
        #pragma unroll
        for (int j = 0; j < 4; ++j) {
            int n = n0 + wc * 64 + j * 16 + l15;
            float bv = bQ[n];   // bo
            #pragma unroll
            for (int i = 0; i < 4; ++i)
                #pragma unroll
                for (int r = 0; r < 4; ++r) {
                    int m = m0 + wr * 64 + i * 16 + quad * 4 + r;
                    oF[(size_t)m * Ddim + n] = acc[i][j][r] + bv;
                }
        }
    }
}

// ---------------- Flash attention: bf16 MFMA, dbuf prefetch ----------------
// Block = 4 waves; wave w owns q rows [q0+16w, +15]. 32-key tiles.
// Register-prefetch K/V tile kt+1 during compute of kt; 1 barrier/tile.
#define FA_BQ 64
#define FA_BK 32

__global__ __launch_bounds__(256)
void flash_mfma(const ushort_t* __restrict__ Q, const ushort_t* __restrict__ K,
                const ushort_t* __restrict__ Vt, ushort_t* __restrict__ ctx)
{
    __shared__ ushort_t Kt[2][32 * 64];     // XOR-swizzled 16B blocks
    __shared__ ushort_t Vs[2][64 * 40];     // [d][key], stride 40
    __shared__ ushort_t PT[4][16 * 40];     // per-wave [q][key], stride 40

    const int tid  = threadIdx.x;
    const int lane = tid & 63;
    const int w    = tid >> 6;
    const int bh   = blockIdx.y;
    const int qb   = (int)gridDim.x - 1 - (int)blockIdx.x;  // longest-first
    const int q0   = qb * FA_BQ;
    const int qw   = q0 + w * 16;
    const int l15  = lane & 15;
    const int quad = lane >> 4;
    const float scale = 0.125f;

    const ushort_t* Qrow = Q + ((size_t)bh * Sdim + qw + l15) * HDdim;
    bfrag Qf0 = *(const bfrag*)(Qrow + quad * 8);
    bfrag Qf1 = *(const bfrag*)(Qrow + 32 + quad * 8);

    const ushort_t* Kp = K  + (size_t)bh * Sdim * HDdim;
    const ushort_t* Vp = Vt + (size_t)bh * HDdim * Sdim;
    ushort_t* PTw = PT[w];

    // staging assignment
    const int krow_s = tid >> 3;            // 0..31
    const int kblk_s = tid & 7;             // 16B block within 128B row
    const int vd_s   = tid >> 2;            // 0..63
    const int vk_s   = (tid & 3) * 8;       // key offset

    f4 O[4];
    #pragma unroll
    for (int c = 0; c < 4; ++c) O[c] = (f4){0.f, 0.f, 0.f, 0.f};
    float m_prev = -INFINITY, l_run = 0.f;

    const int ntiles = (q0 + FA_BQ) / FA_BK;

    // preload tile 0 into registers
    bfrag gK = *(const bfrag*)(Kp + (size_t)krow_s * HDdim + kblk_s * 8);
    bfrag gV = *(const bfrag*)(Vp + (size_t)vd_s * Sdim + vk_s);

    for (int kt = 0; kt < ntiles; ++kt) {
        const int k0  = kt * FA_BK;
        const int buf = kt & 1;

        // commit prefetched tile to LDS (waits the global loads here)
        *(bfrag*)&Kt[buf][krow_s * 64 + ((kblk_s ^ krow_s) & 7) * 8] = gK;
        *(bfrag*)&Vs[buf][vd_s * 40 + vk_s] = gV;
        __syncthreads();

        // issue next tile's loads; latency hidden by this tile's compute
        if (kt + 1 < ntiles) {
            const int k0n = k0 + FA_BK;
            gK = *(const bfrag*)(Kp + (size_t)(k0n + krow_s) * HDdim + kblk_s * 8);
            gV = *(const bfrag*)(Vp + (size_t)vd_s * Sdim + k0n + vk_s);
        }

        if (k0 <= qw + 15) {   // wave has >=1 valid key in this tile
            f4 ST[2];
            #pragma unroll
            for (int h = 0; h < 2; ++h) {
                int krow = h * 16 + l15;
                bfrag a0 = *(const bfrag*)&Kt[buf][krow * 64 + (((0 + quad) ^ krow) & 7) * 8];
                bfrag a1 = *(const bfrag*)&Kt[buf][krow * 64 + (((4 + quad) ^ krow) & 7) * 8];
                f4 s = (f4){0.f, 0.f, 0.f, 0.f};
                s = __builtin_amdgcn_mfma_f32_16x16x32_bf16(a0, Qf0, s, 0, 0, 0);
                s = __builtin_amdgcn_mfma_f32_16x16x32_bf16(a1, Qf1, s, 0, 0, 0);
                ST[h] = s;
            }

            const int q_g = qw + l15;
            float p[2][4];
            float mt = -INFINITY;
            if (k0 + FA_BK - 1 <= qw) {
                // fully valid tile: no mask
                #pragma unroll
                for (int h = 0; h < 2; ++h)
                    #pragma unroll
                    for (int r = 0; r < 4; ++r) {
                        float v = ST[h][r] * scale;
                        p[h][r] = v;
                        mt = fmaxf(mt, v);
                    }
            } else {
                #pragma unroll
                for (int h = 0; h < 2; ++h)
                    #pragma unroll
                    for (int r = 0; r < 4; ++r) {
                        int key_g = k0 + h * 16 + quad * 4 + r;
                        float v = (key_g <= q_g) ? ST[h][r] * scale : -INFINITY;
                        p[h][r] = v;
                        mt = fmaxf(mt, v);
                    }
            }
            mt = fmaxf(mt, __shfl_xor(mt, 16, 64));
            mt = fmaxf(mt, __shfl_xor(mt, 32, 64));
            float m_new = fmaxf(m_prev, mt);
            float alpha = __expf(m_prev - m_new);
            float rsum = 0.f;
            #pragma unroll
            for (int h = 0; h < 2; ++h)
                #pragma unroll
                for (int r = 0; r < 4; ++r) {
                    float e = __expf(p[h][r] - m_new);
                    p[h][r] = e;
                    rsum += e;
                }
            rsum += __shfl_xor(rsum, 16, 64);
            rsum += __shfl_xor(rsum, 32, 64);
            l_run = l_run * alpha + rsum;
            m_prev = m_new;

            // P^T -> PT[q][key], packed 4-ushort (b64) writes
            #pragma unroll
            for (int h = 0; h < 2; ++h) {
                ushort_t pk[4] = {f2bf(p[h][0]), f2bf(p[h][1]),
                                  f2bf(p[h][2]), f2bf(p[h][3])};
                *(uint2*)&PTw[l15 * 40 + h * 16 + quad * 4] = *(const uint2*)pk;
            }

            #pragma unroll
            for (int r = 0; r < 4; ++r) {
                float ar = __shfl(alpha, (lane & 48) + quad * 4 + r, 64);
                #pragma unroll
                for (int c = 0; c < 4; ++c) O[c][r] *= ar;
            }

            bfrag pA = *(const bfrag*)&PTw[l15 * 40 + quad * 8];
            #pragma unroll
            for (int c = 0; c < 4; ++c) {
                bfrag vB = *(const bfrag*)&Vs[buf][(c * 16 + l15) * 40 + quad * 8];
                O[c] = __builtin_amdgcn_mfma_f32_16x16x32_bf16(pA, vB, O[c], 0, 0, 0);
            }
        }
    }

    // epilogue: bf16 ctx [B,S,D]
    const int b = bh >> 4, h = bh & 15;
    #pragma unroll
    for (int r = 0; r < 4; ++r) {
        float inv_l = 1.0f / __shfl(l_run, (lane & 48) + quad * 4 + r, 64);
        size_t base = ((size_t)b * Sdim + qw + quad * 4 + r) * Ddim + h * HDdim + l15;
        #pragma unroll
        for (int c = 0; c < 4; ++c)
            ctx[base + c * 16] = f2bf(O[c][r] * inv_l);
    }
}

// ---------------- launch ----------------
extern "C" void kernel_launch(void* const* d_in, const int* in_sizes, int n_in,
                              void* d_out, int out_size, void* d_ws, size_t ws_size,
                              hipStream_t stream)
{
    const int NX = Mdim * Ddim;
    const int NW = Ddim * Ddim;
    int xi = 0, wi[4] = {1, 3, 5, 7}, bi[4] = {2, 4, 6, 8}, nw = 0, nb = 0;
    bool sized = true;
    for (int i = 0; i < 9; ++i) {
        if (in_sizes[i] == NX) xi = i;
        else if (in_sizes[i] == NW) { if (nw < 4) wi[nw++] = i; }
        else if (in_sizes[i] == Ddim) { if (nb < 4) bi[nb++] = i; }
        else sized = false;
    }
    int iWq, iWk, iWv, iWo, ibq, ibk, ibv, ibo;
    if (!sized || xi == 0) {
        xi = 0; iWq = 1; ibq = 2; iWk = 3; ibk = 4; iWv = 5; ibv = 6; iWo = 7; ibo = 8;
    } else {
        iWk = wi[0]; iWo = wi[1]; iWq = wi[2]; iWv = wi[3];
        ibk = bi[0]; ibo = bi[1]; ibq = bi[2]; ibv = bi[3];
    }

    const float* x  = (const float*)d_in[xi];
    const float* Wq = (const float*)d_in[iWq];
    const float* bq = (const float*)d_in[ibq];
    const float* Wk = (const float*)d_in[iWk];
    const float* bk = (const float*)d_in[ibk];
    const float* Wv = (const float*)d_in[iWv];
    const float* bv = (const float*)d_in[ibv];
    const float* Wo = (const float*)d_in[iWo];
    const float* bo = (const float*)d_in[ibo];
    float* out = (float*)d_out;

    const size_t elems = (size_t)Mdim * Ddim;
    const size_t welems = (size_t)Ddim * Ddim;
    ushort_t* Qb    = (ushort_t*)d_ws;
    ushort_t* Kb    = Qb + elems;
    ushort_t* Vtb   = Kb + elems;
    ushort_t* Cb    = Vtb + elems;
    ushort_t* xb    = Cb + elems;
    ushort_t* qkvT  = xb + elems;
    ushort_t* WoT   = qkvT + 3 * welems;

    dim3 blk(256);
    cast_x<<<dim3(Mdim * Ddim / (256 * 8)), blk, 0, stream>>>(x, xb);
    wtrans<<<dim3(16, 16, 4), blk, 0, stream>>>(Wq, Wk, Wv, Wo, qkvT, WoT);

    gemm_mfma<0><<<dim3(3 * Ddim / 128, Mdim / 128), blk, 0, stream>>>(
        xb, qkvT, bq, bk, bv, Qb, Kb, Vtb, nullptr);

    dim3 gAttn(Sdim / FA_BQ, Bdim * Hn);   // (32, 32)
    flash_mfma<<<gAttn, blk, 0, stream>>>(Qb, Kb, Vtb, Cb);

    gemm_mfma<1><<<dim3(Ddim / 128, Mdim / 128), blk, 0, stream>>>(
        Cb, WoT, bo, nullptr, nullptr, nullptr, nullptr, nullptr, out);
}